// Round 1
// baseline (680.940 us; speedup 1.0000x reference)
//
#include <hip/hip_runtime.h>

// out[b, c, n] = mean[v] + dot(basis[v, :], texcode[b, :])
//   v = 3072*y[n] + 6*x[n] + (2 - c)
//   x[n] = clip(int(uv[n,0]*256), 0, 255)
//   y[n] = clip(int((1-uv[n,1])*256), 0, 255)
// Derivation: tex.reshape(B,512,512,3).transpose(0,3,1,2)[:, :, ::2, ::2][:, ::-1]
//   => flat texture index for (c, i, j) is 3072*i + 6*j + (2-c).

#define B_SZ 8
#define K_SZ 200

__global__ __launch_bounds__(64) void flametex_sample_kernel(
    const float* __restrict__ texcode,  // (8, 200)
    const float* __restrict__ uv,       // (N, 2)
    const float* __restrict__ mean,     // (786432,)
    const float* __restrict__ basis,    // (786432, 200)
    float* __restrict__ out,            // (8, 3, N)
    int N)
{
    const int n    = blockIdx.x;
    const int c    = blockIdx.y;      // output channel
    const int lane = threadIdx.x;     // 0..63

    // Sample coordinates (wave-uniform)
    const float u0 = uv[2 * n + 0];
    const float u1 = uv[2 * n + 1];
    int xi = (int)(u0 * 256.0f);
    xi = min(max(xi, 0), 255);
    int yi = (int)((1.0f - u1) * 256.0f);
    yi = min(max(yi, 0), 255);
    const int v = 3072 * yi + 6 * xi + (2 - c);

    const float* __restrict__ brow = basis + (long long)v * K_SZ;

    float partial[B_SZ];
#pragma unroll
    for (int b = 0; b < B_SZ; ++b) partial[b] = 0.0f;

    // K split across 64 lanes: k = lane, lane+64, lane+128, lane+192 (<200)
    for (int k = lane; k < K_SZ; k += 64) {
        const float bk = brow[k];
#pragma unroll
        for (int b = 0; b < B_SZ; ++b)
            partial[b] += bk * texcode[b * K_SZ + k];
    }

    // Wave reduction over 64 lanes for each of the 8 batch sums
    const float mv = mean[v];
#pragma unroll
    for (int b = 0; b < B_SZ; ++b) {
        float s = partial[b];
#pragma unroll
        for (int off = 32; off > 0; off >>= 1)
            s += __shfl_down(s, off, 64);
        if (lane == 0)
            out[((long long)b * 3 + c) * N + n] = mv + s;
    }
}

extern "C" void kernel_launch(void* const* d_in, const int* in_sizes, int n_in,
                              void* d_out, int out_size, void* d_ws, size_t ws_size,
                              hipStream_t stream) {
    const float* texcode = (const float*)d_in[0];  // (8, 200)
    const float* uv      = (const float*)d_in[1];  // (N, 2)
    const float* mean    = (const float*)d_in[2];  // (1, 1, 786432)
    const float* basis   = (const float*)d_in[3];  // (1, 786432, 200)
    float* out = (float*)d_out;                    // (8, 3, N) float32

    const int N = in_sizes[1] / 2;                 // 5023

    dim3 grid(N, 3);
    flametex_sample_kernel<<<grid, 64, 0, stream>>>(texcode, uv, mean, basis, out, N);
}

// Round 2
// 669.759 us; speedup vs baseline: 1.0167x; 1.0167x over previous
//
#include <hip/hip_runtime.h>

// out[b, c, n] = mean[v] + dot(basis[v, :], texcode[b, :])
//   v = 3072*y[n] + 6*x[n] + (2 - c)
//   x[n] = clip(int(uv[n,0]*256), 0, 255)
//   y[n] = clip(int((1-uv[n,1])*256), 0, 255)
// Derivation: tex.reshape(B,512,512,3).transpose(0,3,1,2)[:, :, ::2, ::2][:, ::-1]
//   => flat texture index for (c, i, j) is 3072*i + 6*j + (2-c).
//
// Structure: 256-thread block = 4 waves; each wave handles one pair p = 3n+c.
// Within a wave: lane = kg*8 + b, kg in [0,8) splits K=200 into 25-chunks,
// b in [0,8) is the batch. Reduction is only 3 shfl_xor steps (over kg bits).
// texcode (8x200 = 6.4 KB) staged in LDS once per block; bank aliasing is
// exactly 2-way everywhere (free on gfx950 — m136).

#define B_SZ 8
#define K_SZ 200
#define PAIRS_PER_BLOCK 4

__global__ __launch_bounds__(256) void flametex_sample_kernel(
    const float* __restrict__ texcode,  // (8, 200)
    const float* __restrict__ uv,       // (N, 2)
    const float* __restrict__ mean,     // (786432,)
    const float* __restrict__ basis,    // (786432, 200)
    float* __restrict__ out,            // (8, 3, N)
    int N)
{
    __shared__ float s_tex[B_SZ * K_SZ];  // 6.4 KB

    const int tid = threadIdx.x;

    // Stage texcode into LDS (coalesced)
    for (int i = tid; i < B_SZ * K_SZ; i += 256)
        s_tex[i] = texcode[i];
    __syncthreads();

    const int p = blockIdx.x * PAIRS_PER_BLOCK + (tid >> 6);  // pair = 3n + c
    if (p >= 3 * N) return;

    const int n = p / 3;
    const int c = p - 3 * n;

    const int lane = tid & 63;
    const int kg   = lane >> 3;   // k-group 0..7 (25 k's each)
    const int b    = lane & 7;    // batch 0..7

    // Sample coordinates (wave-uniform)
    const float u0 = uv[2 * n + 0];
    const float u1 = uv[2 * n + 1];
    int xi = (int)(u0 * 256.0f);
    xi = min(max(xi, 0), 255);
    int yi = (int)((1.0f - u1) * 256.0f);
    yi = min(max(yi, 0), 255);
    const int v = 3072 * yi + 6 * xi + (2 - c);

    const float* __restrict__ brow = basis + (long long)v * K_SZ + kg * 25;
    const float* __restrict__ trow = s_tex + b * K_SZ + kg * 25;

    float acc = 0.0f;
#pragma unroll
    for (int i = 0; i < 25; ++i)
        acc += brow[i] * trow[i];

    // Butterfly over the kg bits (3, 4, 5) — 3 steps total
    acc += __shfl_xor(acc, 8, 64);
    acc += __shfl_xor(acc, 16, 64);
    acc += __shfl_xor(acc, 32, 64);

    if (kg == 0)
        out[((long long)b * 3 + c) * N + n] = mean[v] + acc;
}

extern "C" void kernel_launch(void* const* d_in, const int* in_sizes, int n_in,
                              void* d_out, int out_size, void* d_ws, size_t ws_size,
                              hipStream_t stream) {
    const float* texcode = (const float*)d_in[0];  // (8, 200)
    const float* uv      = (const float*)d_in[1];  // (N, 2)
    const float* mean    = (const float*)d_in[2];  // (1, 1, 786432)
    const float* basis   = (const float*)d_in[3];  // (1, 786432, 200)
    float* out = (float*)d_out;                    // (8, 3, N) float32

    const int N = in_sizes[1] / 2;                 // 5023
    const int total = 3 * N;                       // 15069 pairs
    const int blocks = (total + PAIRS_PER_BLOCK - 1) / PAIRS_PER_BLOCK;

    flametex_sample_kernel<<<blocks, 256, 0, stream>>>(texcode, uv, mean, basis, out, N);
}